// Round 1
// baseline (270.805 us; speedup 1.0000x reference)
//
#include <hip/hip_runtime.h>
#include <hip/hip_bf16.h>

// ---------------- problem constants ----------------
#define Bc   8
#define Cc   256
#define Hc   64
#define Wc   64
#define Mc   4
#define Rc   4
#define HWc  4096
#define KDIM 1024          // M*C
#define NROW 32768         // B*H*W

#define F_OUT_SIZE 8388608        // B*C*H*W
#define LOSS_IDX   8388608
#define OFFS_BASE  8388609        // offsets output base in d_out

// ---------------- ws layout (bytes) ----------------
#define FCT_OFF    0u              // f32 [B][H][W][C]     33,554,432
#define HEAD_OFF   33554432u       // bf16 [NROW][KDIM]    67,108,864
#define WBF_OFF    100663296u      // bf16 [C][KDIM]          524,288
#define ATTN_OFF   101187584u      // f32 [B][M][HW]          524,288
#define ALPHA_OFF  101711872u      // f32 [8]
#define LOSSP_OFF  101712128u      // f32 [512]

typedef unsigned short u16;
typedef __attribute__((ext_vector_type(8))) short bf16x8;
typedef __attribute__((ext_vector_type(4))) float f32x4;

static __device__ __forceinline__ u16 f2bf(float f) {
    unsigned int u = __float_as_uint(f);
    unsigned int r = (u + 0x7FFFu + ((u >> 16) & 1u)) >> 16;
    return (u16)r;
}

// ---------------- kernel 1: transpose F_c -> [b][hw][c] fp32 ----------------
__global__ __launch_bounds__(256) void transpose_fc(const float* __restrict__ Fc,
                                                    float* __restrict__ Fct) {
    __shared__ float tile[32][33];
    int blk = blockIdx.x;
    int b   = blk >> 10;
    int rem = blk & 1023;
    int hw0 = (rem >> 3) << 5;
    int c0  = (rem & 7) << 5;
    int tid = threadIdx.x;
#pragma unroll
    for (int it = 0; it < 4; ++it) {
        int idx = it * 256 + tid;
        int ci = idx >> 5, hwi = idx & 31;
        tile[ci][hwi] = Fc[(((size_t)b << 8) + c0 + ci) * HWc + hw0 + hwi];
    }
    __syncthreads();
#pragma unroll
    for (int it = 0; it < 4; ++it) {
        int idx = it * 256 + tid;
        int hwi = idx >> 5, ci = idx & 31;
        Fct[(((size_t)b << 12) + hw0 + hwi) * Cc + c0 + ci] = tile[ci][hwi];
    }
}

// ---------------- kernel 2: cast w_fuse -> bf16 [co][k] ----------------
__global__ __launch_bounds__(256) void cast_wfuse(const float* __restrict__ wf,
                                                  u16* __restrict__ wbf) {
    int i = blockIdx.x * 256 + threadIdx.x;      // 65536 groups of 4
    float4 v = *(const float4*)(wf + (size_t)i * 4);
    ushort4 o;
    o.x = f2bf(v.x); o.y = f2bf(v.y); o.z = f2bf(v.z); o.w = f2bf(v.w);
    *(ushort4*)(wbf + (size_t)i * 4) = o;
}

// ---------------- kernel 3: 3x3 conv -> offsets(d_out) + attn(ws) + loss partials ----------------
__global__ __launch_bounds__(256) void conv_off_attn(
    const float* __restrict__ Fx, const float* __restrict__ Fc,
    const float* __restrict__ w_off, const float* __restrict__ b_off,
    const float* __restrict__ w_attn, const float* __restrict__ b_attn,
    float* __restrict__ dout, float* __restrict__ attnb, float* __restrict__ lossp) {
    __shared__ float rows[4][3][66];
    __shared__ float red[4][12][64];
    __shared__ float wr4[4];

    const int tid = threadIdx.x;
    const int wv = tid >> 6, lane = tid & 63;
    const int b = blockIdx.x >> 6, h = blockIdx.x & 63;

    if (lane < 3) { rows[wv][lane][0] = 0.f; rows[wv][lane][65] = 0.f; }

    float acc[12];
#pragma unroll
    for (int i = 0; i < 12; ++i) acc[i] = 0.f;

    for (int i = 0; i < 128; ++i) {
        const int cc = wv * 128 + i;
        const int cu = __builtin_amdgcn_readfirstlane(cc);
        const float* plane = (cu < 256)
            ? Fx + (((size_t)b << 8) + cu) * HWc
            : Fc + (((size_t)b << 8) + (cu - 256)) * HWc;
        rows[wv][0][lane + 1] = (h > 0)  ? plane[(h - 1) * 64 + lane] : 0.f;
        rows[wv][1][lane + 1] =            plane[h * 64 + lane];
        rows[wv][2][lane + 1] = (h < 63) ? plane[(h + 1) * 64 + lane] : 0.f;
        __builtin_amdgcn_wave_barrier();
        float n[3][3];
#pragma unroll
        for (int ky = 0; ky < 3; ++ky)
#pragma unroll
            for (int kx = 0; kx < 3; ++kx)
                n[ky][kx] = rows[wv][ky][lane + kx];
        __builtin_amdgcn_wave_barrier();
#pragma unroll
        for (int oc = 0; oc < 12; ++oc) {
            const float* wp = (oc < 8)
                ? w_off  + ((size_t)(oc * 512) + cu) * 9
                : w_attn + ((size_t)((oc - 8) * 512) + cu) * 9;
#pragma unroll
            for (int t9 = 0; t9 < 9; ++t9)
                acc[oc] = fmaf(wp[t9], n[t9 / 3][t9 % 3], acc[oc]);
        }
    }

#pragma unroll
    for (int oc = 0; oc < 12; ++oc) red[wv][oc][lane] = acc[oc];
    __syncthreads();

    float labs = 0.f;
    for (int idx = tid; idx < 768; idx += 256) {
        int oc = idx >> 6, w = idx & 63;
        float s = red[0][oc][w] + red[1][oc][w] + red[2][oc][w] + red[3][oc][w];
        if (oc < 8) {
            float v = s + b_off[oc];
            dout[OFFS_BASE + (((size_t)b * 8 + oc) << 12) + (h << 6) + w] = v;
            labs += fabsf(v);
        } else {
            float a = s + b_attn[oc - 8];
            attnb[(((size_t)b * 4 + (oc - 8)) << 12) + (h << 6) + w] = 1.f / (1.f + expf(-a));
        }
    }
#pragma unroll
    for (int off = 32; off; off >>= 1) labs += __shfl_down(labs, off);
    if (lane == 0) wr4[wv] = labs;
    __syncthreads();
    if (tid == 0) lossp[blockIdx.x] = wr4[0] + wr4[1] + wr4[2] + wr4[3];
}

// ---------------- kernel 4: loss reduce + alpha MLP ----------------
__global__ __launch_bounds__(256) void finalize_small(
    const float* __restrict__ lossp, const float* __restrict__ t,
    const float* __restrict__ w1, const float* __restrict__ b1,
    const float* __restrict__ w2, const float* __restrict__ b2,
    float* __restrict__ dout, float* __restrict__ alpha) {
    __shared__ float sd[4];
    const int tid = threadIdx.x;
    float s = 0.f;
    for (int i = tid; i < 512; i += 256) s += lossp[i];
#pragma unroll
    for (int off = 32; off; off >>= 1) s += __shfl_down(s, off);
    if ((tid & 63) == 0) sd[tid >> 6] = s;
    __syncthreads();
    if (tid == 0) dout[LOSS_IDX] = (sd[0] + sd[1] + sd[2] + sd[3]) * (1.f / 262144.f);

    for (int b = 0; b < 8; ++b) {
        __syncthreads();
        float v = 0.f;
        if (tid < 128) v = fmaxf(fmaf(t[b], w1[tid], b1[tid]), 0.f) * w2[tid];
#pragma unroll
        for (int off = 32; off; off >>= 1) v += __shfl_down(v, off);
        if ((tid & 63) == 0) sd[tid >> 6] = v;
        __syncthreads();
        if (tid == 0) alpha[b] = 1.f / (1.f + expf(-(sd[0] + sd[1] + b2[0])));
    }
}

// ---------------- kernel 5: bilinear gather -> head (bf16) ----------------
__global__ __launch_bounds__(256) void sample_head(
    const float* __restrict__ Fct, const float* __restrict__ dout,
    const float* __restrict__ attnb, const float* __restrict__ Wp,
    u16* __restrict__ head) {
    const int tid = threadIdx.x;
    const int wv = tid >> 6, lane = tid & 63;
    const int item = blockIdx.x * 4 + wv;           // (b, m, p)
    const int b = item >> 14;
    const int m = (item >> 12) & 3;
    const int p = item & 4095;
    const int h = p >> 6, wc = p & 63;

    const float off0 = dout[OFFS_BASE + (((size_t)b * 8 + 2 * m) << 12) + p];
    const float off1 = dout[OFFS_BASE + (((size_t)b * 8 + 2 * m + 1) << 12) + p];
    const float a    = attnb[(((size_t)b * 4 + m) << 12) + p];

    const float ysh = -1.f + h * (2.f / 63.f);
    const float xsw = -1.f + wc * (2.f / 63.f);

    const float* base = Fct + (((size_t)b << 12) * Cc);
    float ax = 0.f, ay = 0.f, az = 0.f, aw = 0.f;

#pragma unroll
    for (int r = 0; r < 4; ++r) {
        const float bpy = (r < 2) ? -0.5f : 0.5f;
        const float bpx = (r & 1) ? 0.5f : -0.5f;
        const float c0 = ysh + bpy + off0;   // used as gx (reference quirk)
        const float c1 = xsw + bpx + off1;   // used as gy
        const float ix = (c0 + 1.f) * 31.5f;
        const float iy = (c1 + 1.f) * 31.5f;
        const float x0 = floorf(ix), y0 = floorf(iy);
        const float wx1 = ix - x0, wx0 = 1.f - wx1;
        const float wy1 = iy - y0, wy0 = 1.f - wy1;
        const float wr = Wp[m * 4 + r];
#pragma unroll
        for (int c4 = 0; c4 < 4; ++c4) {
            const int dy = c4 >> 1, dx = c4 & 1;
            const float yf = y0 + dy, xf = x0 + dx;
            if (yf >= 0.f && yf < 64.f && xf >= 0.f && xf < 64.f) {
                const int yi = (int)yf, xi = (int)xf;
                const float w = wr * (dy ? wy1 : wy0) * (dx ? wx1 : wx0);
                const float4 v = *(const float4*)(base + ((size_t)((yi << 6) + xi)) * Cc + (lane << 2));
                ax = fmaf(w, v.x, ax); ay = fmaf(w, v.y, ay);
                az = fmaf(w, v.z, az); aw = fmaf(w, v.w, aw);
            }
        }
    }
    const size_t row = ((size_t)b << 12) + p;
    ushort4 o;
    o.x = f2bf(a * ax); o.y = f2bf(a * ay); o.z = f2bf(a * az); o.w = f2bf(a * aw);
    *(ushort4*)(head + row * KDIM + (m << 8) + (lane << 2)) = o;
}

// ---------------- kernel 6: fuse GEMM (bf16 MFMA) + blend epilogue ----------------
__global__ __launch_bounds__(256) void fuse_gemm(
    const u16* __restrict__ head, const u16* __restrict__ wbf,
    const float* __restrict__ Fx, const float* __restrict__ bfuse,
    const float* __restrict__ alpha, float* __restrict__ dout) {
    __shared__ u16 Asl[128 * 32];   // [row(pix)][k]
    __shared__ u16 Bsl[128 * 32];   // [col(co)][k]

    const int tid = threadIdx.x;
    const int lane = tid & 63, wv = tid >> 6;
    const int wm = wv >> 1, wn = wv & 1;
    const int l15 = lane & 15, g = lane >> 4;
    const size_t arow0 = (size_t)blockIdx.x * 128;
    const int co0 = blockIdx.y * 128;

    f32x4 acc[4][4] = {};

    const int row0 = tid >> 2, kc0 = (tid & 3) * 8;
    const int row1 = (tid + 256) >> 2, kc1 = ((tid + 256) & 3) * 8;

    for (int kt = 0; kt < 32; ++kt) {
        const int k0 = kt * 32;
        uint4 a0 = *(const uint4*)(head + (arow0 + row0) * KDIM + k0 + kc0);
        uint4 b0 = *(const uint4*)(wbf + (size_t)(co0 + row0) * KDIM + k0 + kc0);
        uint4 a1 = *(const uint4*)(head + (arow0 + row1) * KDIM + k0 + kc1);
        uint4 b1 = *(const uint4*)(wbf + (size_t)(co0 + row1) * KDIM + k0 + kc1);
        __syncthreads();
        *(uint4*)&Asl[tid * 8] = a0;
        *(uint4*)&Asl[(tid + 256) * 8] = a1;
        *(uint4*)&Bsl[tid * 8] = b0;
        *(uint4*)&Bsl[(tid + 256) * 8] = b1;
        __syncthreads();

        bf16x8 af[4], bf[4];
#pragma unroll
        for (int f = 0; f < 4; ++f) {
            af[f] = *(const bf16x8*)&Asl[(wm * 64 + f * 16 + l15) * 32 + g * 8];
            bf[f] = *(const bf16x8*)&Bsl[(wn * 64 + f * 16 + l15) * 32 + g * 8];
        }
#pragma unroll
        for (int i = 0; i < 4; ++i)
#pragma unroll
            for (int j = 0; j < 4; ++j)
                acc[i][j] = __builtin_amdgcn_mfma_f32_16x16x32_bf16(af[i], bf[j], acc[i][j], 0, 0, 0);
    }

    const int b = (int)(arow0 >> 12);
    const float al = alpha[b], il = 1.f - al;
    const int pixbase = (int)(arow0 & 4095);
#pragma unroll
    for (int i = 0; i < 4; ++i) {
        const int rowl = wm * 64 + i * 16 + g * 4;
        const int pix = pixbase + rowl;
#pragma unroll
        for (int j = 0; j < 4; ++j) {
            const int co = co0 + wn * 64 + j * 16 + l15;
            const float bias = bfuse[co];
            const size_t idx = (((size_t)b << 8) + co) * HWc + pix;
            const float4 fx = *(const float4*)(Fx + idx);
            const f32x4 v = acc[i][j];
            float4 o;
            o.x = al * (v[0] + bias) + il * fx.x;
            o.y = al * (v[1] + bias) + il * fx.y;
            o.z = al * (v[2] + bias) + il * fx.z;
            o.w = al * (v[3] + bias) + il * fx.w;
            *(float4*)(dout + idx) = o;
        }
    }
}

// ---------------- launcher ----------------
extern "C" void kernel_launch(void* const* d_in, const int* in_sizes, int n_in,
                              void* d_out, int out_size, void* d_ws, size_t ws_size,
                              hipStream_t stream) {
    const float* F_x    = (const float*)d_in[0];
    const float* F_c    = (const float*)d_in[1];
    const float* t      = (const float*)d_in[2];
    const float* w_off  = (const float*)d_in[3];
    const float* b_off  = (const float*)d_in[4];
    const float* w_attn = (const float*)d_in[5];
    const float* b_attn = (const float*)d_in[6];
    const float* Wp     = (const float*)d_in[7];
    const float* w_fuse = (const float*)d_in[8];
    const float* b_fuse = (const float*)d_in[9];
    const float* w1     = (const float*)d_in[10];
    const float* b1     = (const float*)d_in[11];
    const float* w2     = (const float*)d_in[12];
    const float* b2     = (const float*)d_in[13];
    float* out = (float*)d_out;

    char* ws = (char*)d_ws;
    float* Fct   = (float*)(ws + FCT_OFF);
    u16*   head  = (u16*)(ws + HEAD_OFF);
    u16*   wbf   = (u16*)(ws + WBF_OFF);
    float* attnb = (float*)(ws + ATTN_OFF);
    float* alphb = (float*)(ws + ALPHA_OFF);
    float* lossp = (float*)(ws + LOSSP_OFF);

    transpose_fc<<<dim3(8192), dim3(256), 0, stream>>>(F_c, Fct);
    cast_wfuse<<<dim3(256), dim3(256), 0, stream>>>(w_fuse, wbf);
    conv_off_attn<<<dim3(512), dim3(256), 0, stream>>>(F_x, F_c, w_off, b_off,
                                                       w_attn, b_attn, out, attnb, lossp);
    finalize_small<<<dim3(1), dim3(256), 0, stream>>>(lossp, t, w1, b1, w2, b2, out, alphb);
    sample_head<<<dim3(32768), dim3(256), 0, stream>>>(Fct, out, attnb, Wp, head);
    fuse_gemm<<<dim3(256, 2), dim3(256), 0, stream>>>(head, wbf, F_x, b_fuse, alphb, out);
}

// Round 2
// 168.637 us; speedup vs baseline: 1.6058x; 1.6058x over previous
//
#include <hip/hip_runtime.h>
#include <hip/hip_bf16.h>

// ---------------- problem constants ----------------
#define Bc   8
#define Cc   256
#define Hc   64
#define Wc   64
#define Mc   4
#define Rc   4
#define HWc  4096
#define KDIM 1024          // M*C
#define NROW 32768         // B*H*W

#define F_OUT_SIZE 8388608        // B*C*H*W
#define LOSS_IDX   8388608
#define OFFS_BASE  8388609        // offsets output base in d_out

// ---------------- ws layout (bytes) ----------------
#define FCT_OFF    0u              // f32 [B][H][W][C]     33,554,432
#define HEAD_OFF   33554432u       // bf16 [NROW][KDIM]    67,108,864  (also conv partials, earlier in stream)
#define WBF_OFF    100663296u      // bf16 [C][KDIM]          524,288
#define ATTN_OFF   101187584u      // f32 [B][M][HW]          524,288
#define ALPHA_OFF  101711872u      // f32 [8]
#define LOSSP_OFF  101712128u      // f32 [512]

typedef unsigned short u16;
typedef __attribute__((ext_vector_type(8))) short bf16x8;
typedef __attribute__((ext_vector_type(4))) float f32x4;

static __device__ __forceinline__ u16 f2bf(float f) {
    unsigned int u = __float_as_uint(f);
    unsigned int r = (u + 0x7FFFu + ((u >> 16) & 1u)) >> 16;
    return (u16)r;
}

// ---------------- kernel 1: transpose F_c -> [b][hw][c] fp32 ----------------
__global__ __launch_bounds__(256) void transpose_fc(const float* __restrict__ Fc,
                                                    float* __restrict__ Fct) {
    __shared__ float tile[32][33];
    int blk = blockIdx.x;
    int b   = blk >> 10;
    int rem = blk & 1023;
    int hw0 = (rem >> 3) << 5;
    int c0  = (rem & 7) << 5;
    int tid = threadIdx.x;
#pragma unroll
    for (int it = 0; it < 4; ++it) {
        int idx = it * 256 + tid;
        int ci = idx >> 5, hwi = idx & 31;
        tile[ci][hwi] = Fc[(((size_t)b << 8) + c0 + ci) * HWc + hw0 + hwi];
    }
    __syncthreads();
#pragma unroll
    for (int it = 0; it < 4; ++it) {
        int idx = it * 256 + tid;
        int hwi = idx >> 5, ci = idx & 31;
        Fct[(((size_t)b << 12) + hw0 + hwi) * Cc + c0 + ci] = tile[ci][hwi];
    }
}

// ---------------- kernel 2: cast w_fuse -> bf16 [co][k] ----------------
__global__ __launch_bounds__(256) void cast_wfuse(const float* __restrict__ wf,
                                                  u16* __restrict__ wbf) {
    int i = blockIdx.x * 256 + threadIdx.x;      // 65536 groups of 4
    float4 v = *(const float4*)(wf + (size_t)i * 4);
    ushort4 o;
    o.x = f2bf(v.x); o.y = f2bf(v.y); o.z = f2bf(v.z); o.w = f2bf(v.w);
    *(ushort4*)(wbf + (size_t)i * 4) = o;
}

// ---------------- kernel 3: 3x3 conv v2 -> per-channel-group partials ----------------
// grid: (b*4+q, cg) = (32, 16); block 256. Thread owns 4 consecutive pixels.
// partials layout: [cg][b][oc(12)][4096] f32  (25.2 MB, lives in head region)
__global__ __launch_bounds__(256) void conv_v2(
    const float* __restrict__ Fx, const float* __restrict__ Fc,
    const float* __restrict__ w_off, const float* __restrict__ w_attn,
    float* __restrict__ partials) {
    __shared__ float lds[18][72];

    const int tid = threadIdx.x;
    const int bq = blockIdx.x;
    const int cg = blockIdx.y;
    const int b = bq >> 2, q = bq & 3;
    const int rq = tid >> 4;             // row in quarter [0,16)
    const int c  = (tid & 15) << 2;      // pixel col base {0,4,...,60}

    // zero halo columns (never overwritten by staging)
    if (tid < 18) { lds[tid][3] = 0.f; lds[tid][68] = 0.f; }

    float acc[12][4] = {};

    const int i0 = tid;          // float4 slot 0
    const int i1 = tid + 256;    // float4 slot 1 (only tid<32)
    const int r0 = i0 >> 4, c0w = (i0 & 15) << 2;
    const int r1 = i1 >> 4, c1w = (i1 & 15) << 2;
    const int g0 = (q << 4) - 1 + r0;
    const int g1 = (q << 4) - 1 + r1;

    auto plane_for = [&](int chi) -> const float* {
        const int ch = cg * 32 + chi;
        return (ch < 256) ? Fx + (((size_t)b << 8) + ch) * HWc
                          : Fc + (((size_t)b << 8) + (ch - 256)) * HWc;
    };

    const float4 fz = {0.f, 0.f, 0.f, 0.f};
    const float* pl = plane_for(0);
    float4 v0 = (g0 >= 0 && g0 < 64) ? *(const float4*)(pl + g0 * 64 + c0w) : fz;
    float4 v1 = (tid < 32 && g1 >= 0 && g1 < 64) ? *(const float4*)(pl + g1 * 64 + c1w) : fz;

    for (int chi = 0; chi < 32; ++chi) {
        __syncthreads();                               // prev compute done
        *(float4*)&lds[r0][4 + c0w] = v0;
        if (tid < 32) *(float4*)&lds[r1][4 + c1w] = v1;
        if (chi < 31) {
            const float* pn = plane_for(chi + 1);
            v0 = (g0 >= 0 && g0 < 64) ? *(const float4*)(pn + g0 * 64 + c0w) : fz;
            if (tid < 32) v1 = (g1 >= 0 && g1 < 64) ? *(const float4*)(pn + g1 * 64 + c1w) : fz;
        }
        __syncthreads();                               // tile ready

        float a[3][6];
#pragma unroll
        for (int dy = 0; dy < 3; ++dy)
#pragma unroll
            for (int k = 0; k < 6; ++k)
                a[dy][k] = lds[rq + dy][c + 3 + k];

        const int ch = cg * 32 + chi;                  // wave-uniform
#pragma unroll
        for (int oc = 0; oc < 12; ++oc) {
            const float* wp = (oc < 8)
                ? w_off  + ((size_t)(oc * 512) + ch) * 9
                : w_attn + ((size_t)((oc - 8) * 512) + ch) * 9;
#pragma unroll
            for (int t9 = 0; t9 < 9; ++t9) {
                const float w = wp[t9];
                const int dy = t9 / 3, dx = t9 % 3;
#pragma unroll
                for (int p = 0; p < 4; ++p)
                    acc[oc][p] = fmaf(w, a[dy][p + dx], acc[oc][p]);
            }
        }
    }

    const size_t pbase = (((size_t)cg * 8 + b) * 12) * HWc + (q << 10) + (rq << 6) + c;
#pragma unroll
    for (int oc = 0; oc < 12; ++oc) {
        float4 o; o.x = acc[oc][0]; o.y = acc[oc][1]; o.z = acc[oc][2]; o.w = acc[oc][3];
        *(float4*)(partials + pbase + (size_t)oc * HWc) = o;
    }
}

// ---------------- kernel 3b: reduce partials -> offsets/attn + loss partials ----------------
// grid 384 x 256; each thread: one float4 of one (b,oc)
__global__ __launch_bounds__(256) void conv_reduce(
    const float* __restrict__ partials, const float* __restrict__ b_off,
    const float* __restrict__ b_attn, float* __restrict__ dout,
    float* __restrict__ attnb, float* __restrict__ lossp) {
    __shared__ float wr4[4];
    const int tid = threadIdx.x;
    const int i = blockIdx.x * 256 + tid;            // [0, 98304)
    const int boc = i >> 10;                         // uniform per block
    const int b = boc / 12, oc = boc % 12;
    const int pg = (i & 1023) << 2;

    float4 s = {0.f, 0.f, 0.f, 0.f};
#pragma unroll
    for (int cg = 0; cg < 16; ++cg) {
        const float4 v = *(const float4*)(partials + ((((size_t)cg * 8 + b) * 12 + oc) << 12) + pg);
        s.x += v.x; s.y += v.y; s.z += v.z; s.w += v.w;
    }

    float labs = 0.f;
    if (oc < 8) {
        const float bo = b_off[oc];
        s.x += bo; s.y += bo; s.z += bo; s.w += bo;
        *(float4*)(dout + OFFS_BASE + (((size_t)b * 8 + oc) << 12) + pg) = s;
        labs = fabsf(s.x) + fabsf(s.y) + fabsf(s.z) + fabsf(s.w);
    } else {
        const float ba = b_attn[oc - 8];
        float4 o;
        o.x = 1.f / (1.f + expf(-(s.x + ba)));
        o.y = 1.f / (1.f + expf(-(s.y + ba)));
        o.z = 1.f / (1.f + expf(-(s.z + ba)));
        o.w = 1.f / (1.f + expf(-(s.w + ba)));
        *(float4*)(attnb + (((size_t)b * 4 + (oc - 8)) << 12) + pg) = o;
    }
#pragma unroll
    for (int off = 32; off; off >>= 1) labs += __shfl_down(labs, off);
    if ((tid & 63) == 0) wr4[tid >> 6] = labs;
    __syncthreads();
    if (tid == 0) lossp[blockIdx.x] = wr4[0] + wr4[1] + wr4[2] + wr4[3];
}

// ---------------- kernel 4: loss reduce + alpha MLP ----------------
__global__ __launch_bounds__(256) void finalize_small(
    const float* __restrict__ lossp, const float* __restrict__ t,
    const float* __restrict__ w1, const float* __restrict__ b1,
    const float* __restrict__ w2, const float* __restrict__ b2,
    float* __restrict__ dout, float* __restrict__ alpha) {
    __shared__ float sd[4];
    const int tid = threadIdx.x;
    float s = 0.f;
    for (int i = tid; i < 384; i += 256) s += lossp[i];
#pragma unroll
    for (int off = 32; off; off >>= 1) s += __shfl_down(s, off);
    if ((tid & 63) == 0) sd[tid >> 6] = s;
    __syncthreads();
    if (tid == 0) dout[LOSS_IDX] = (sd[0] + sd[1] + sd[2] + sd[3]) * (1.f / 262144.f);

    for (int b = 0; b < 8; ++b) {
        __syncthreads();
        float v = 0.f;
        if (tid < 128) v = fmaxf(fmaf(t[b], w1[tid], b1[tid]), 0.f) * w2[tid];
#pragma unroll
        for (int off = 32; off; off >>= 1) v += __shfl_down(v, off);
        if ((tid & 63) == 0) sd[tid >> 6] = v;
        __syncthreads();
        if (tid == 0) alpha[b] = 1.f / (1.f + expf(-(sd[0] + sd[1] + b2[0])));
    }
}

// ---------------- kernel 5: bilinear gather -> head (bf16) ----------------
__global__ __launch_bounds__(256) void sample_head(
    const float* __restrict__ Fct, const float* __restrict__ dout,
    const float* __restrict__ attnb, const float* __restrict__ Wp,
    u16* __restrict__ head) {
    const int tid = threadIdx.x;
    const int wv = tid >> 6, lane = tid & 63;
    const int item = blockIdx.x * 4 + wv;           // (b, m, p)
    const int b = item >> 14;
    const int m = (item >> 12) & 3;
    const int p = item & 4095;
    const int h = p >> 6, wc = p & 63;

    const float off0 = dout[OFFS_BASE + (((size_t)b * 8 + 2 * m) << 12) + p];
    const float off1 = dout[OFFS_BASE + (((size_t)b * 8 + 2 * m + 1) << 12) + p];
    const float a    = attnb[(((size_t)b * 4 + m) << 12) + p];

    const float ysh = -1.f + h * (2.f / 63.f);
    const float xsw = -1.f + wc * (2.f / 63.f);

    const float* base = Fct + (((size_t)b << 12) * Cc);
    float ax = 0.f, ay = 0.f, az = 0.f, aw = 0.f;

#pragma unroll
    for (int r = 0; r < 4; ++r) {
        const float bpy = (r < 2) ? -0.5f : 0.5f;
        const float bpx = (r & 1) ? 0.5f : -0.5f;
        const float c0 = ysh + bpy + off0;   // used as gx (reference quirk)
        const float c1 = xsw + bpx + off1;   // used as gy
        const float ix = (c0 + 1.f) * 31.5f;
        const float iy = (c1 + 1.f) * 31.5f;
        const float x0 = floorf(ix), y0 = floorf(iy);
        const float wx1 = ix - x0, wx0 = 1.f - wx1;
        const float wy1 = iy - y0, wy0 = 1.f - wy1;
        const float wr = Wp[m * 4 + r];
#pragma unroll
        for (int c4 = 0; c4 < 4; ++c4) {
            const int dy = c4 >> 1, dx = c4 & 1;
            const float yf = y0 + dy, xf = x0 + dx;
            if (yf >= 0.f && yf < 64.f && xf >= 0.f && xf < 64.f) {
                const int yi = (int)yf, xi = (int)xf;
                const float w = wr * (dy ? wy1 : wy0) * (dx ? wx1 : wx0);
                const float4 v = *(const float4*)(base + ((size_t)((yi << 6) + xi)) * Cc + (lane << 2));
                ax = fmaf(w, v.x, ax); ay = fmaf(w, v.y, ay);
                az = fmaf(w, v.z, az); aw = fmaf(w, v.w, aw);
            }
        }
    }
    const size_t row = ((size_t)b << 12) + p;
    ushort4 o;
    o.x = f2bf(a * ax); o.y = f2bf(a * ay); o.z = f2bf(a * az); o.w = f2bf(a * aw);
    *(ushort4*)(head + row * KDIM + (m << 8) + (lane << 2)) = o;
}

// ---------------- kernel 6: fuse GEMM (bf16 MFMA) + blend epilogue ----------------
__global__ __launch_bounds__(256) void fuse_gemm(
    const u16* __restrict__ head, const u16* __restrict__ wbf,
    const float* __restrict__ Fx, const float* __restrict__ bfuse,
    const float* __restrict__ alpha, float* __restrict__ dout) {
    __shared__ u16 Asl[128 * 32];   // [row(pix)][k]
    __shared__ u16 Bsl[128 * 32];   // [col(co)][k]

    const int tid = threadIdx.x;
    const int lane = tid & 63, wv = tid >> 6;
    const int wm = wv >> 1, wn = wv & 1;
    const int l15 = lane & 15, g = lane >> 4;
    const size_t arow0 = (size_t)blockIdx.x * 128;
    const int co0 = blockIdx.y * 128;

    f32x4 acc[4][4] = {};

    const int row0 = tid >> 2, kc0 = (tid & 3) * 8;
    const int row1 = (tid + 256) >> 2, kc1 = ((tid + 256) & 3) * 8;

    for (int kt = 0; kt < 32; ++kt) {
        const int k0 = kt * 32;
        uint4 a0 = *(const uint4*)(head + (arow0 + row0) * KDIM + k0 + kc0);
        uint4 b0 = *(const uint4*)(wbf + (size_t)(co0 + row0) * KDIM + k0 + kc0);
        uint4 a1 = *(const uint4*)(head + (arow0 + row1) * KDIM + k0 + kc1);
        uint4 b1 = *(const uint4*)(wbf + (size_t)(co0 + row1) * KDIM + k0 + kc1);
        __syncthreads();
        *(uint4*)&Asl[tid * 8] = a0;
        *(uint4*)&Asl[(tid + 256) * 8] = a1;
        *(uint4*)&Bsl[tid * 8] = b0;
        *(uint4*)&Bsl[(tid + 256) * 8] = b1;
        __syncthreads();

        bf16x8 af[4], bf[4];
#pragma unroll
        for (int f = 0; f < 4; ++f) {
            af[f] = *(const bf16x8*)&Asl[(wm * 64 + f * 16 + l15) * 32 + g * 8];
            bf[f] = *(const bf16x8*)&Bsl[(wn * 64 + f * 16 + l15) * 32 + g * 8];
        }
#pragma unroll
        for (int i = 0; i < 4; ++i)
#pragma unroll
            for (int j = 0; j < 4; ++j)
                acc[i][j] = __builtin_amdgcn_mfma_f32_16x16x32_bf16(af[i], bf[j], acc[i][j], 0, 0, 0);
    }

    const int b = (int)(arow0 >> 12);
    const float al = alpha[b], il = 1.f - al;
    const int pixbase = (int)(arow0 & 4095);
#pragma unroll
    for (int i = 0; i < 4; ++i) {
        const int rowl = wm * 64 + i * 16 + g * 4;
        const int pix = pixbase + rowl;
#pragma unroll
        for (int j = 0; j < 4; ++j) {
            const int co = co0 + wn * 64 + j * 16 + l15;
            const float bias = bfuse[co];
            const size_t idx = (((size_t)b << 8) + co) * HWc + pix;
            const float4 fx = *(const float4*)(Fx + idx);
            const f32x4 v = acc[i][j];
            float4 o;
            o.x = al * (v[0] + bias) + il * fx.x;
            o.y = al * (v[1] + bias) + il * fx.y;
            o.z = al * (v[2] + bias) + il * fx.z;
            o.w = al * (v[3] + bias) + il * fx.w;
            *(float4*)(dout + idx) = o;
        }
    }
}

// ---------------- launcher ----------------
extern "C" void kernel_launch(void* const* d_in, const int* in_sizes, int n_in,
                              void* d_out, int out_size, void* d_ws, size_t ws_size,
                              hipStream_t stream) {
    const float* F_x    = (const float*)d_in[0];
    const float* F_c    = (const float*)d_in[1];
    const float* t      = (const float*)d_in[2];
    const float* w_off  = (const float*)d_in[3];
    const float* b_off  = (const float*)d_in[4];
    const float* w_attn = (const float*)d_in[5];
    const float* b_attn = (const float*)d_in[6];
    const float* Wp     = (const float*)d_in[7];
    const float* w_fuse = (const float*)d_in[8];
    const float* b_fuse = (const float*)d_in[9];
    const float* w1     = (const float*)d_in[10];
    const float* b1     = (const float*)d_in[11];
    const float* w2     = (const float*)d_in[12];
    const float* b2     = (const float*)d_in[13];
    float* out = (float*)d_out;

    char* ws = (char*)d_ws;
    float* Fct   = (float*)(ws + FCT_OFF);
    u16*   head  = (u16*)(ws + HEAD_OFF);
    float* parts = (float*)(ws + HEAD_OFF);   // reuse head region for conv partials
    u16*   wbf   = (u16*)(ws + WBF_OFF);
    float* attnb = (float*)(ws + ATTN_OFF);
    float* alphb = (float*)(ws + ALPHA_OFF);
    float* lossp = (float*)(ws + LOSSP_OFF);

    transpose_fc<<<dim3(8192), dim3(256), 0, stream>>>(F_c, Fct);
    cast_wfuse<<<dim3(256), dim3(256), 0, stream>>>(w_fuse, wbf);
    conv_v2<<<dim3(32, 16), dim3(256), 0, stream>>>(F_x, F_c, w_off, w_attn, parts);
    conv_reduce<<<dim3(384), dim3(256), 0, stream>>>(parts, b_off, b_attn, out, attnb, lossp);
    finalize_small<<<dim3(1), dim3(256), 0, stream>>>(lossp, t, w1, b1, w2, b2, out, alphb);
    sample_head<<<dim3(32768), dim3(256), 0, stream>>>(Fct, out, attnb, Wp, head);
    fuse_gemm<<<dim3(256, 2), dim3(256), 0, stream>>>(head, wbf, F_x, b_fuse, alphb, out);
}